// Round 1
// baseline (685.509 us; speedup 1.0000x reference)
//
#include <hip/hip_runtime.h>
#include <math.h>

#define CCH   256                 // channels C
#define HWSZ  3136                // H*W
#define NBAT  32                  // N
#define MCOLS (NBAT*HWSZ)         // 100352 columns

// stats layout (floats) at d_ws + C*M
#define S_MN     0     // channel sums -> means
#define S_OFFS   256   // offs[i] = sum_c u[c,i]*mn[c]
#define S_DMAX   512
#define S_DMIN   768
#define S_QSUM   1024  // row sums of q -> qmean
#define S_ROWADD 1280  // mn[i] - sum_c u[i,c]*qmean[c]
#define S_SCALE  1536
#define S_STEP   1792
#define S_TOTAL  2048

__device__ __forceinline__ void atomicMaxF(float* addr, float v){
    if (v >= 0.f) atomicMax((int*)addr, __float_as_int(v));
    else          atomicMin((unsigned int*)addr, (unsigned int)__float_as_int(v));
}
__device__ __forceinline__ void atomicMinF(float* addr, float v){
    if (v >= 0.f) atomicMin((int*)addr, __float_as_int(v));
    else          atomicMax((unsigned int*)addr, (unsigned int)__float_as_int(v));
}

// ---------------- K0: init stats ----------------
__global__ void k_init(float* __restrict__ stats){
    int t = blockIdx.x * 256 + threadIdx.x;
    if (t < S_TOTAL){
        float v = 0.f;
        if (t >= S_DMAX && t < S_DMIN)      v = -INFINITY;
        else if (t >= S_DMIN && t < S_QSUM) v =  INFINITY;
        stats[t] = v;
    }
}

// ---------------- K1: per-channel sum of relu(x) ----------------
__global__ __launch_bounds__(256) void k_chansum(const float* __restrict__ x,
                                                 float* __restrict__ stats){
    int c     = blockIdx.x & 255;
    int chunk = blockIdx.x >> 8;     // 0..7, 4 images each
    int t = threadIdx.x;
    float s = 0.f;
    for (int n = chunk*4; n < chunk*4 + 4; ++n){
        const float* base = x + ((size_t)(n*CCH + c)) * HWSZ;
        for (int i = t; i < HWSZ; i += 256){
            float v = base[i];
            s += (v > 0.f) ? v : 0.f;
        }
    }
    __shared__ float red[256];
    red[t] = s; __syncthreads();
    for (int o = 128; o > 0; o >>= 1){
        if (t < o) red[t] += red[t + o];
        __syncthreads();
    }
    if (t == 0) atomicAdd(&stats[S_MN + c], red[0]);
}

// ---------------- K1b: mn, offs ----------------
__global__ void k_stats1(const float* __restrict__ u, float* __restrict__ stats){
    int i = threadIdx.x;   // 256 threads, 1 block
    float mn = stats[S_MN + i] * (1.f / (float)MCOLS);
    stats[S_MN + i] = mn;
    __syncthreads();
    float o = 0.f;
    for (int c = 0; c < CCH; ++c) o += u[(size_t)c*CCH + i] * stats[S_MN + c];
    stats[S_OFFS + i] = o;
}

// ---------------- K2: p = clamp(u^T relu(x) - offs), track row min/max ----------------
__global__ __launch_bounds__(256) void k_gemm1(const float* __restrict__ x,
                                               const float* __restrict__ u,
                                               const float* __restrict__ clampVal,
                                               float* __restrict__ p,
                                               float* __restrict__ stats){
    __shared__ __align__(16) float sA[16][68];   // [cc][i]  (pad 68: <=2-way banks, 16B aligned)
    __shared__ __align__(16) float sB[16][64];   // [cc][m]
    const int m0 = blockIdx.x * 64;
    const int i0 = blockIdx.y * 64;
    const int n   = m0 / HWSZ;            // tile never straddles n (3136 % 64 == 0)
    const int hw0 = m0 - n * HWSZ;
    const int t  = threadIdx.x;
    const int tx = t & 15, ty = t >> 4;
    const int la_c = t >> 4, la_i4 = t & 15;   // A loader: 16 rows x 16 float4
    const int lb_c = t >> 4, lb_m4 = t & 15;   // B loader

    float acc[4][4] = {};
    for (int k0 = 0; k0 < CCH; k0 += 16){
        float4 av = *(const float4*)&u[(size_t)(k0 + la_c)*CCH + i0 + la_i4*4];
        *(float4*)&sA[la_c][la_i4*4] = av;
        float4 bv = *(const float4*)&x[((size_t)(n*CCH + k0 + lb_c))*HWSZ + hw0 + lb_m4*4];
        bv.x = fmaxf(bv.x, 0.f); bv.y = fmaxf(bv.y, 0.f);
        bv.z = fmaxf(bv.z, 0.f); bv.w = fmaxf(bv.w, 0.f);
        *(float4*)&sB[lb_c][lb_m4*4] = bv;
        __syncthreads();
        #pragma unroll
        for (int cc = 0; cc < 16; ++cc){
            const float4 a = *(const float4*)&sA[cc][ty*4];
            const float4 b = *(const float4*)&sB[cc][tx*4];
            const float ar[4] = {a.x, a.y, a.z, a.w};
            const float br[4] = {b.x, b.y, b.z, b.w};
            #pragma unroll
            for (int r = 0; r < 4; ++r)
                #pragma unroll
                for (int s = 0; s < 4; ++s)
                    acc[r][s] = fmaf(ar[r], br[s], acc[r][s]);
        }
        __syncthreads();
    }
    // epilogue: subtract offs, clamp, store, row min/max -> atomics
    #pragma unroll
    for (int r = 0; r < 4; ++r){
        int i = i0 + ty*4 + r;
        float off = stats[S_OFFS + i];
        float cv  = clampVal[i];
        float4 v;
        v.x = fminf(fmaxf(acc[r][0] - off, -cv), cv);
        v.y = fminf(fmaxf(acc[r][1] - off, -cv), cv);
        v.z = fminf(fmaxf(acc[r][2] - off, -cv), cv);
        v.w = fminf(fmaxf(acc[r][3] - off, -cv), cv);
        *(float4*)&p[(size_t)i*MCOLS + m0 + tx*4] = v;
        float mx = fmaxf(fmaxf(v.x, v.y), fmaxf(v.z, v.w));
        float mv = fminf(fminf(v.x, v.y), fminf(v.z, v.w));
        #pragma unroll
        for (int o = 1; o < 16; o <<= 1){
            mx = fmaxf(mx, __shfl_xor(mx, o));
            mv = fminf(mv, __shfl_xor(mv, o));
        }
        if (tx == 0){
            atomicMaxF(&stats[S_DMAX + i], mx);
            atomicMinF(&stats[S_DMIN + i], mv);
        }
    }
}

// ---------------- K3: row sums of quantized p ----------------
__global__ __launch_bounds__(256) void k_qsum(const float* __restrict__ p,
                                              const int* __restrict__ abw,
                                              float* __restrict__ stats){
    const int row   = blockIdx.x >> 3;
    const int chunk = blockIdx.x & 7;
    const int ab = *abw;
    const float dmax = stats[S_DMAX + row], dmin = stats[S_DMIN + row];
    const bool doq = (ab < 17) && (dmax != dmin);
    const float levels = (float)((1 << ab) - 1);
    const float scale = doq ? levels / (dmax - dmin) : 0.f;
    const float step  = doq ? 1.f / scale : 0.f;
    const float4* base = (const float4*)(p + (size_t)row*MCOLS + chunk*(MCOLS/8));
    float s = 0.f;
    for (int idx = threadIdx.x; idx < (MCOLS/8)/4; idx += 256){
        float4 v = base[idx];
        if (doq){
            v.x = fmaf(rintf((v.x - dmin)*scale), step, dmin);
            v.y = fmaf(rintf((v.y - dmin)*scale), step, dmin);
            v.z = fmaf(rintf((v.z - dmin)*scale), step, dmin);
            v.w = fmaf(rintf((v.w - dmin)*scale), step, dmin);
        }
        s += (v.x + v.y) + (v.z + v.w);
    }
    __shared__ float red[256];
    red[threadIdx.x] = s; __syncthreads();
    for (int o = 128; o > 0; o >>= 1){
        if (threadIdx.x < o) red[threadIdx.x] += red[threadIdx.x + o];
        __syncthreads();
    }
    if (threadIdx.x == 0) atomicAdd(&stats[S_QSUM + row], red[0]);
}

// ---------------- K3b: qmean, rowadd, scale/step arrays ----------------
__global__ void k_stats2(const float* __restrict__ u, const int* __restrict__ abw,
                         float* __restrict__ stats){
    int i = threadIdx.x;   // 256 threads, 1 block
    int ab = *abw;
    float qmean = stats[S_QSUM + i] * (1.f / (float)MCOLS);
    stats[S_QSUM + i] = qmean;
    float dmax = stats[S_DMAX + i], dmin = stats[S_DMIN + i];
    bool doq = (ab < 17) && (dmax != dmin);
    float levels = (float)((1 << ab) - 1);
    float scale = doq ? levels / (dmax - dmin) : 0.f;
    stats[S_SCALE + i] = scale;
    stats[S_STEP + i]  = doq ? 1.f / scale : 0.f;
    __syncthreads();
    float rsum = 0.f;
    for (int c = 0; c < CCH; ++c) rsum += u[(size_t)i*CCH + c] * stats[S_QSUM + c];
    stats[S_ROWADD + i] = stats[S_MN + i] - rsum;
}

// ---------------- K4: out = u * q(p) + rowadd, NCHW write ----------------
__global__ __launch_bounds__(256) void k_gemm2(const float* __restrict__ p,
                                               const float* __restrict__ u,
                                               float* __restrict__ out,
                                               const float* __restrict__ stats){
    __shared__ __align__(16) float sA[16][68];   // [cc][i]
    __shared__ __align__(16) float sB[16][64];   // [cc][m]
    const int m0 = blockIdx.x * 64;
    const int i0 = blockIdx.y * 64;
    const int n   = m0 / HWSZ;
    const int hw0 = m0 - n * HWSZ;
    const int t  = threadIdx.x;
    const int tx = t & 15, ty = t >> 4;
    const int la_i = t >> 2, la_c4 = t & 3;     // A loader: 64 rows x 4 float4 along c
    const int lb_c = t >> 4, lb_m4 = t & 15;

    float acc[4][4] = {};
    for (int k0 = 0; k0 < CCH; k0 += 16){
        float4 av = *(const float4*)&u[(size_t)(i0 + la_i)*CCH + k0 + la_c4*4];
        sA[la_c4*4 + 0][la_i] = av.x;
        sA[la_c4*4 + 1][la_i] = av.y;
        sA[la_c4*4 + 2][la_i] = av.z;
        sA[la_c4*4 + 3][la_i] = av.w;
        const int row = k0 + lb_c;
        const float scale = stats[S_SCALE + row];
        const float step  = stats[S_STEP + row];
        const float dmin  = stats[S_DMIN + row];
        float4 bv = *(const float4*)&p[(size_t)row*MCOLS + m0 + lb_m4*4];
        if (scale > 0.f){
            bv.x = fmaf(rintf((bv.x - dmin)*scale), step, dmin);
            bv.y = fmaf(rintf((bv.y - dmin)*scale), step, dmin);
            bv.z = fmaf(rintf((bv.z - dmin)*scale), step, dmin);
            bv.w = fmaf(rintf((bv.w - dmin)*scale), step, dmin);
        }
        *(float4*)&sB[lb_c][lb_m4*4] = bv;
        __syncthreads();
        #pragma unroll
        for (int cc = 0; cc < 16; ++cc){
            const float4 a = *(const float4*)&sA[cc][ty*4];
            const float4 b = *(const float4*)&sB[cc][tx*4];
            const float ar[4] = {a.x, a.y, a.z, a.w};
            const float br[4] = {b.x, b.y, b.z, b.w};
            #pragma unroll
            for (int r = 0; r < 4; ++r)
                #pragma unroll
                for (int s = 0; s < 4; ++s)
                    acc[r][s] = fmaf(ar[r], br[s], acc[r][s]);
        }
        __syncthreads();
    }
    #pragma unroll
    for (int r = 0; r < 4; ++r){
        int i = i0 + ty*4 + r;
        float ra = stats[S_ROWADD + i];
        float4 v = { acc[r][0] + ra, acc[r][1] + ra, acc[r][2] + ra, acc[r][3] + ra };
        *(float4*)&out[((size_t)(n*CCH + i))*HWSZ + hw0 + tx*4] = v;
    }
}

extern "C" void kernel_launch(void* const* d_in, const int* in_sizes, int n_in,
                              void* d_out, int out_size, void* d_ws, size_t ws_size,
                              hipStream_t stream){
    const float* x  = (const float*)d_in[0];
    const float* u  = (const float*)d_in[1];
    const float* cv = (const float*)d_in[2];
    const int*   ab = (const int*)d_in[3];
    float* out = (float*)d_out;
    float* p     = (float*)d_ws;                       // C*M floats (102.8 MB)
    float* stats = p + (size_t)CCH * MCOLS;            // 2048 floats

    k_init   <<<8, 256, 0, stream>>>(stats);
    k_chansum<<<2048, 256, 0, stream>>>(x, stats);
    k_stats1 <<<1, 256, 0, stream>>>(u, stats);
    k_gemm1  <<<dim3(MCOLS/64, CCH/64), 256, 0, stream>>>(x, u, cv, p, stats);
    k_qsum   <<<2048, 256, 0, stream>>>(p, ab, stats);
    k_stats2 <<<1, 256, 0, stream>>>(u, ab, stats);
    k_gemm2  <<<dim3(MCOLS/64, CCH/64), 256, 0, stream>>>(p, u, out, stats);
}

// Round 2
// 453.434 us; speedup vs baseline: 1.5118x; 1.5118x over previous
//
#include <hip/hip_runtime.h>
#include <math.h>

using short8  = __attribute__((ext_vector_type(8))) short;
using floatx4 = __attribute__((ext_vector_type(4))) float;
typedef unsigned short ushort;

#define CCH   256
#define HWSZ  3136
#define NBAT  32
#define MCOLS (NBAT*HWSZ)   // 100352

// stats slots (floats)
#define S_MN     0
#define S_OFFS   256
#define S_DMAX   512
#define S_DMIN   768
#define S_QSUM   1024
#define S_ROWADD 1280
#define S_TOTAL  1536

__device__ __forceinline__ ushort f2bf(float f){
    unsigned u = __float_as_uint(f);
    u += 0x7FFFu + ((u >> 16) & 1u);       // round-to-nearest-even
    return (ushort)(u >> 16);
}
__device__ __forceinline__ float bf2f(ushort h){
    return __uint_as_float(((unsigned)h) << 16);
}
__device__ __forceinline__ void atomicMaxF(float* addr, float v){
    if (v >= 0.f) atomicMax((int*)addr, __float_as_int(v));
    else          atomicMin((unsigned*)addr, (unsigned)__float_as_int(v));
}
__device__ __forceinline__ void atomicMinF(float* addr, float v){
    if (v >= 0.f) atomicMin((int*)addr, __float_as_int(v));
    else          atomicMax((unsigned*)addr, (unsigned)__float_as_int(v));
}
__device__ __forceinline__ void gld_lds16(const void* g, void* l){
    __builtin_amdgcn_global_load_lds((const __attribute__((address_space(1))) void*)g,
                                     (__attribute__((address_space(3))) void*)l, 16, 0, 0);
}

// ---------------- K0: init stats ----------------
__global__ void k_init(float* __restrict__ stats){
    int t = blockIdx.x * 256 + threadIdx.x;
    if (t < S_TOTAL){
        float v = 0.f;
        if (t >= S_DMAX && t < S_DMIN)      v = -__builtin_inff();
        else if (t >= S_DMIN && t < S_QSUM) v =  __builtin_inff();
        stats[t] = v;
    }
}

// ---------------- K_prep: u -> uT_hi/lo [i][c], u_hi/lo [i][c] (bf16 split) ----------------
__global__ void k_prep(const float* __restrict__ u, ushort* __restrict__ uThi,
                       ushort* __restrict__ uTlo, ushort* __restrict__ uhi,
                       ushort* __restrict__ ulo){
    int i = blockIdx.x, c = threadIdx.x;
    float vt = u[(size_t)c*CCH + i];
    ushort h = f2bf(vt);
    uThi[i*CCH + c] = h;
    uTlo[i*CCH + c] = f2bf(vt - bf2f(h));
    float vd = u[(size_t)i*CCH + c];
    ushort h2 = f2bf(vd);
    uhi[i*CCH + c] = h2;
    ulo[i*CCH + c] = f2bf(vd - bf2f(h2));
}

// ---------------- K_trans: xbT[m][c] = bf16(relu(x)), + channel sums ----------------
__global__ __launch_bounds__(256) void k_trans(const float* __restrict__ x,
                                               ushort* __restrict__ xbT,
                                               float* __restrict__ stats){
    __shared__ float tile[64*66];   // [hw][c], stride 66 (8B-aligned float2 reads, <=4-way banks)
    __shared__ float csum[64];
    const int hwb = blockIdx.x*64, cb = blockIdx.y*64, n = blockIdx.z;
    const int t = threadIdx.x, lane = t & 63;
    #pragma unroll
    for (int pass = 0; pass < 4; ++pass){
        int c  = cb + pass*16 + (t >> 4);
        int hw = hwb + (t & 15)*4;
        float4 v = *(const float4*)&x[((size_t)(n*CCH + c))*HWSZ + hw];
        v.x = fmaxf(v.x, 0.f); v.y = fmaxf(v.y, 0.f);
        v.z = fmaxf(v.z, 0.f); v.w = fmaxf(v.w, 0.f);
        int hl = (t & 15)*4;
        int cl = pass*16 + (t >> 4);
        tile[(hl+0)*66 + cl] = v.x;
        tile[(hl+1)*66 + cl] = v.y;
        tile[(hl+2)*66 + cl] = v.z;
        tile[(hl+3)*66 + cl] = v.w;
        float sv = (v.x + v.y) + (v.z + v.w);
        #pragma unroll
        for (int o = 1; o < 16; o <<= 1) sv += __shfl_xor(sv, o);
        if ((lane & 15) == 0) csum[cl] = sv;
    }
    __syncthreads();
    {   // transposed write: thread t -> row hw = t>>2, c-chunk (t&3)*16
        int hl = t >> 2, cs = (t & 3)*16;
        short8 o0, o1;
        #pragma unroll
        for (int j = 0; j < 8; j += 2){
            float2 f2 = *(float2*)&tile[hl*66 + cs + j];
            o0[j]   = (short)f2bf(f2.x);
            o0[j+1] = (short)f2bf(f2.y);
        }
        #pragma unroll
        for (int j = 0; j < 8; j += 2){
            float2 f2 = *(float2*)&tile[hl*66 + cs + 8 + j];
            o1[j]   = (short)f2bf(f2.x);
            o1[j+1] = (short)f2bf(f2.y);
        }
        size_t m = (size_t)n*HWSZ + hwb + hl;
        ushort* dst = xbT + m*CCH + cb + cs;
        *(short8*)dst       = o0;
        *(short8*)(dst + 8) = o1;
    }
    if (t < 64) atomicAdd(&stats[S_MN + cb + t], csum[t]);
}

// ---------------- K_stats1: mn, offs ----------------
__global__ void k_stats1(const float* __restrict__ u, float* __restrict__ stats){
    int i = threadIdx.x;
    __shared__ float mn[256];
    float m = stats[S_MN + i] * (1.f/(float)MCOLS);
    stats[S_MN + i] = m;
    mn[i] = m;
    __syncthreads();
    float o = 0.f;
    for (int c = 0; c < CCH; ++c) o += u[(size_t)c*CCH + i] * mn[c];
    stats[S_OFFS + i] = o;
}

// ---------------- K_gemm1: pT[m][i] = bf16(clamp(uT*xb - offs)), row min/max ----------------
__global__ __launch_bounds__(256) void k_gemm1(const ushort* __restrict__ xbT,
                                               const ushort* __restrict__ uThi,
                                               const ushort* __restrict__ uTlo,
                                               const float* __restrict__ clampVal,
                                               float* __restrict__ stats,
                                               ushort* __restrict__ pT){
    __shared__ __align__(16) ushort sAh[128*64];
    __shared__ __align__(16) ushort sAl[128*64];
    __shared__ __align__(16) ushort sB [128*64];
    const int i0 = blockIdx.x * 128;
    const int m0 = blockIdx.y * 128;
    const int t = threadIdx.x;
    const int lane = t & 63, wave = t >> 6;
    const int wi = wave & 1, wm = wave >> 1;
    const int col = lane & 15, quad = lane >> 4;

    floatx4 acc[4][4] = {};
    for (int kt = 0; kt < 4; ++kt){
        const int k0 = kt*64;
        #pragma unroll
        for (int j = 0; j < 4; ++j){
            const int cid = j*256 + t;
            const int row = cid >> 3;
            const int sc  = (cid & 7) ^ (row & 7);
            gld_lds16(uThi + (size_t)(i0+row)*CCH + k0 + sc*8, sAh + cid*8);
            gld_lds16(uTlo + (size_t)(i0+row)*CCH + k0 + sc*8, sAl + cid*8);
            gld_lds16(xbT  + (size_t)(m0+row)*CCH + k0 + sc*8, sB  + cid*8);
        }
        __syncthreads();
        #pragma unroll
        for (int ks = 0; ks < 2; ++ks){
            const int ch = ks*4 + quad;
            short8 bf[4], ah[4], al[4];
            #pragma unroll
            for (int fm = 0; fm < 4; ++fm){
                int r = wm*64 + fm*16 + col;
                bf[fm] = *(const short8*)(sB + r*64 + ((ch ^ (r & 7))*8));
            }
            #pragma unroll
            for (int fi = 0; fi < 4; ++fi){
                int r = wi*64 + fi*16 + col;
                int a = r*64 + ((ch ^ (r & 7))*8);
                ah[fi] = *(const short8*)(sAh + a);
                al[fi] = *(const short8*)(sAl + a);
            }
            #pragma unroll
            for (int fi = 0; fi < 4; ++fi)
                #pragma unroll
                for (int fm = 0; fm < 4; ++fm){
                    acc[fi][fm] = __builtin_amdgcn_mfma_f32_16x16x32_bf16(al[fi], bf[fm], acc[fi][fm], 0, 0, 0);
                    acc[fi][fm] = __builtin_amdgcn_mfma_f32_16x16x32_bf16(ah[fi], bf[fm], acc[fi][fm], 0, 0, 0);
                }
        }
        __syncthreads();
    }
    // epilogue
    const int ibase = i0 + wi*64;
    float mnv[4][4], mxv[4][4];
    #pragma unroll
    for (int fi = 0; fi < 4; ++fi)
        #pragma unroll
        for (int r = 0; r < 4; ++r){ mnv[fi][r] = __builtin_inff(); mxv[fi][r] = -__builtin_inff(); }
    #pragma unroll
    for (int fi = 0; fi < 4; ++fi){
        float offv[4], cvv[4];
        #pragma unroll
        for (int r = 0; r < 4; ++r){
            int i = ibase + fi*16 + quad*4 + r;
            offv[r] = stats[S_OFFS + i];
            cvv[r]  = clampVal[i];
        }
        #pragma unroll
        for (int fm = 0; fm < 4; ++fm){
            int m = m0 + wm*64 + fm*16 + col;
            ushort pk[4];
            #pragma unroll
            for (int r = 0; r < 4; ++r){
                float v = acc[fi][fm][r] - offv[r];
                v = fminf(fmaxf(v, -cvv[r]), cvv[r]);
                ushort h = f2bf(v);
                float vr = bf2f(h);
                pk[r] = h;
                mnv[fi][r] = fminf(mnv[fi][r], vr);
                mxv[fi][r] = fmaxf(mxv[fi][r], vr);
            }
            ushort4 q4 = make_ushort4(pk[0], pk[1], pk[2], pk[3]);
            *(ushort4*)(pT + (size_t)m*CCH + ibase + fi*16 + quad*4) = q4;
        }
    }
    #pragma unroll
    for (int fi = 0; fi < 4; ++fi)
        #pragma unroll
        for (int r = 0; r < 4; ++r){
            float mn = mnv[fi][r], mx = mxv[fi][r];
            #pragma unroll
            for (int o = 1; o < 16; o <<= 1){
                mn = fminf(mn, __shfl_xor(mn, o));
                mx = fmaxf(mx, __shfl_xor(mx, o));
            }
            if (col == 0){
                int i = ibase + fi*16 + quad*4 + r;
                atomicMinF(&stats[S_DMIN + i], mn);
                atomicMaxF(&stats[S_DMAX + i], mx);
            }
        }
}

// ---------------- K_qsum: quantize pT in place (bf16 q), row sums ----------------
__global__ __launch_bounds__(256) void k_qsum(ushort* __restrict__ pT,
                                              const int* __restrict__ abw,
                                              float* __restrict__ stats){
    const int t = threadIdx.x;
    const int kc = t & 31;      // k-chunk (8 k)
    const int ml = t >> 5;      // 0..7
    const int kk = kc * 8;
    const int ab = *abw;
    const float levels = (float)(((ab < 31) ? (1 << ab) : 2) - 1);
    float dmn[8], scl[8], stp[8];
    #pragma unroll
    for (int j = 0; j < 8; ++j){
        float dmax = stats[S_DMAX + kk + j], dmin = stats[S_DMIN + kk + j];
        bool doq = (ab < 17) && (dmax != dmin);
        scl[j] = doq ? levels / (dmax - dmin) : 0.f;
        stp[j] = doq ? (dmax - dmin) / levels : 0.f;
        dmn[j] = dmin;
    }
    float s[8] = {0,0,0,0,0,0,0,0};
    const int mb = blockIdx.x * 128;
    for (int it = 0; it < 16; ++it){
        int m = mb + it*8 + ml;
        short8 v = *(short8*)(pT + (size_t)m*CCH + kk);
        #pragma unroll
        for (int j = 0; j < 8; ++j){
            float f = bf2f((ushort)v[j]);
            if (scl[j] > 0.f){
                f = fmaf(rintf((f - dmn[j])*scl[j]), stp[j], dmn[j]);
                v[j] = (short)f2bf(f);
                f = bf2f((ushort)v[j]);
            }
            s[j] += f;
        }
        *(short8*)(pT + (size_t)m*CCH + kk) = v;
    }
    __shared__ float red[256*8];
    #pragma unroll
    for (int j = 0; j < 8; ++j) red[(kk + j)*8 + ml] = s[j];
    __syncthreads();
    float tot = 0.f;
    #pragma unroll
    for (int q = 0; q < 8; ++q) tot += red[t*8 + q];
    atomicAdd(&stats[S_QSUM + t], tot);
}

// ---------------- K_stats2: qmean, rowadd ----------------
__global__ void k_stats2(const float* __restrict__ u, float* __restrict__ stats){
    int i = threadIdx.x;
    __shared__ float qm[256];
    float q = stats[S_QSUM + i] * (1.f/(float)MCOLS);
    qm[i] = q;
    __syncthreads();
    float rs = 0.f;
    for (int c = 0; c < CCH; ++c) rs += u[(size_t)i*CCH + c] * qm[c];
    stats[S_ROWADD + i] = stats[S_MN + i] - rs;
}

// ---------------- K_gemm2: out = u*q + rowadd (NCHW fp32) ----------------
__global__ __launch_bounds__(256) void k_gemm2(const ushort* __restrict__ qbT,
                                               const ushort* __restrict__ uhi,
                                               const ushort* __restrict__ ulo,
                                               float* __restrict__ out,
                                               const float* __restrict__ stats){
    __shared__ __align__(16) ushort sAh[128*64];
    __shared__ __align__(16) ushort sAl[128*64];
    __shared__ __align__(16) ushort sB [128*64];
    const int i0 = blockIdx.x * 128;
    const int m0 = blockIdx.y * 128;
    const int t = threadIdx.x;
    const int lane = t & 63, wave = t >> 6;
    const int wi = wave & 1, wm = wave >> 1;
    const int col = lane & 15, quad = lane >> 4;

    floatx4 acc[4][4] = {};
    for (int kt = 0; kt < 4; ++kt){
        const int k0 = kt*64;
        #pragma unroll
        for (int j = 0; j < 4; ++j){
            const int cid = j*256 + t;
            const int row = cid >> 3;
            const int sc  = (cid & 7) ^ (row & 7);
            gld_lds16(uhi + (size_t)(i0+row)*CCH + k0 + sc*8, sAh + cid*8);
            gld_lds16(ulo + (size_t)(i0+row)*CCH + k0 + sc*8, sAl + cid*8);
            gld_lds16(qbT + (size_t)(m0+row)*CCH + k0 + sc*8, sB  + cid*8);
        }
        __syncthreads();
        #pragma unroll
        for (int ks = 0; ks < 2; ++ks){
            const int ch = ks*4 + quad;
            short8 bf[4], ah[4], al[4];
            #pragma unroll
            for (int fm = 0; fm < 4; ++fm){
                int r = wm*64 + fm*16 + col;
                bf[fm] = *(const short8*)(sB + r*64 + ((ch ^ (r & 7))*8));
            }
            #pragma unroll
            for (int fi = 0; fi < 4; ++fi){
                int r = wi*64 + fi*16 + col;
                int a = r*64 + ((ch ^ (r & 7))*8);
                ah[fi] = *(const short8*)(sAh + a);
                al[fi] = *(const short8*)(sAl + a);
            }
            #pragma unroll
            for (int fi = 0; fi < 4; ++fi)
                #pragma unroll
                for (int fm = 0; fm < 4; ++fm){
                    acc[fi][fm] = __builtin_amdgcn_mfma_f32_16x16x32_bf16(al[fi], bf[fm], acc[fi][fm], 0, 0, 0);
                    acc[fi][fm] = __builtin_amdgcn_mfma_f32_16x16x32_bf16(ah[fi], bf[fm], acc[fi][fm], 0, 0, 0);
                }
        }
        __syncthreads();
    }
    const int ibase = i0 + wi*64;
    float radd[4][4];
    #pragma unroll
    for (int fi = 0; fi < 4; ++fi)
        #pragma unroll
        for (int r = 0; r < 4; ++r)
            radd[fi][r] = stats[S_ROWADD + ibase + fi*16 + quad*4 + r];
    #pragma unroll
    for (int fm = 0; fm < 4; ++fm){
        int m = m0 + wm*64 + fm*16 + col;
        int n = m / HWSZ;
        int hw = m - n*HWSZ;
        size_t obase = ((size_t)(n*CCH))*HWSZ + hw;
        #pragma unroll
        for (int fi = 0; fi < 4; ++fi)
            #pragma unroll
            for (int r = 0; r < 4; ++r){
                int i = ibase + fi*16 + quad*4 + r;
                out[obase + (size_t)i*HWSZ] = acc[fi][fm][r] + radd[fi][r];
            }
    }
}

extern "C" void kernel_launch(void* const* d_in, const int* in_sizes, int n_in,
                              void* d_out, int out_size, void* d_ws, size_t ws_size,
                              hipStream_t stream){
    const float* x  = (const float*)d_in[0];
    const float* u  = (const float*)d_in[1];
    const float* cv = (const float*)d_in[2];
    const int*   ab = (const int*)d_in[3];
    float* out = (float*)d_out;

    ushort* xbT  = (ushort*)d_out;                     // scratch inside out (51.4MB < 102.8MB)
    ushort* pT   = (ushort*)d_ws;                      // 51.4MB
    ushort* uThi = pT + (size_t)MCOLS*CCH;
    ushort* uTlo = uThi + CCH*CCH;
    ushort* uhi  = uTlo + CCH*CCH;
    ushort* ulo  = uhi  + CCH*CCH;
    float*  stats = (float*)(ulo + CCH*CCH);

    k_init  <<<6, 256, 0, stream>>>(stats);
    k_prep  <<<256, 256, 0, stream>>>(u, uThi, uTlo, uhi, ulo);
    k_trans <<<dim3(49, 4, 32), 256, 0, stream>>>(x, xbT, stats);
    k_stats1<<<1, 256, 0, stream>>>(u, stats);
    k_gemm1 <<<dim3(2, 784), 256, 0, stream>>>(xbT, uThi, uTlo, cv, stats, pT);
    k_qsum  <<<784, 256, 0, stream>>>(pT, ab, stats);
    k_stats2<<<1, 256, 0, stream>>>(u, stats);
    k_gemm2 <<<dim3(2, 784), 256, 0, stream>>>(pT, uhi, ulo, out, stats);
}

// Round 4
// 390.394 us; speedup vs baseline: 1.7559x; 1.1615x over previous
//
#include <hip/hip_runtime.h>
#include <math.h>

typedef unsigned short ushort;
using half8   = __attribute__((ext_vector_type(8))) _Float16;
using short8  = __attribute__((ext_vector_type(8))) short;
using floatx4 = __attribute__((ext_vector_type(4))) float;

#define CCH   256
#define HWSZ  3136
#define NBAT  32
#define MCOLS (NBAT*HWSZ)   // 100352
#define MB    784           // m-blocks (BM=128)

// stats slots (floats)
#define S_MN     0
#define S_OFFS   256
#define S_DMAX   512
#define S_DMIN   768
#define S_QSUM   1024
#define S_ROWADD 1280
#define S_SCALE  1536
#define S_STEP   1792
#define S_TOTAL  2048

__device__ __forceinline__ ushort f2h(float f){
    _Float16 h = (_Float16)f;               // v_cvt_f16_f32, RNE
    return __builtin_bit_cast(ushort, h);
}
__device__ __forceinline__ float h2f(ushort u){
    return (float)__builtin_bit_cast(_Float16, u);
}
__device__ __forceinline__ void atomicMaxF(float* addr, float v){
    if (v >= 0.f) atomicMax((int*)addr, __float_as_int(v));
    else          atomicMin((unsigned*)addr, (unsigned)__float_as_int(v));
}
__device__ __forceinline__ void atomicMinF(float* addr, float v){
    if (v >= 0.f) atomicMin((int*)addr, __float_as_int(v));
    else          atomicMax((unsigned*)addr, (unsigned)__float_as_int(v));
}
__device__ __forceinline__ void gld_lds16(const void* g, void* l){
    __builtin_amdgcn_global_load_lds((const __attribute__((address_space(1))) void*)g,
                                     (__attribute__((address_space(3))) void*)l, 16, 0, 0);
}

// ---------------- K0: init stats ----------------
__global__ void k_init(float* __restrict__ stats){
    int t = blockIdx.x * 256 + threadIdx.x;
    if (t < S_TOTAL){
        float v = 0.f;
        if (t >= S_DMAX && t < S_DMIN)      v = -__builtin_inff();
        else if (t >= S_DMIN && t < S_QSUM) v =  __builtin_inff();
        stats[t] = v;
    }
}

// ---------------- K_prep: u -> uTh[i][c]=fp16(u[c][i]), uh[i][c]=fp16(u[i][c]) ----------------
__global__ void k_prep(const float* __restrict__ u, ushort* __restrict__ uTh,
                       ushort* __restrict__ uh){
    int i = blockIdx.x, c = threadIdx.x;
    uTh[i*CCH + c] = f2h(u[(size_t)c*CCH + i]);
    uh [i*CCH + c] = f2h(u[(size_t)i*CCH + c]);
}

// ---------------- K_trans: xT[m][c] = fp16(relu(x)), + channel sums ----------------
__global__ __launch_bounds__(256) void k_trans(const float* __restrict__ x,
                                               ushort* __restrict__ xT,
                                               float* __restrict__ stats){
    __shared__ float tile[64*66];
    __shared__ float csum[64];
    const int hwb = blockIdx.x*64, cb = blockIdx.y*64, n = blockIdx.z;
    const int t = threadIdx.x, lane = t & 63;
    #pragma unroll
    for (int pass = 0; pass < 4; ++pass){
        int c  = cb + pass*16 + (t >> 4);
        int hw = hwb + (t & 15)*4;
        float4 v = *(const float4*)&x[((size_t)(n*CCH + c))*HWSZ + hw];
        v.x = fmaxf(v.x, 0.f); v.y = fmaxf(v.y, 0.f);
        v.z = fmaxf(v.z, 0.f); v.w = fmaxf(v.w, 0.f);
        int hl = (t & 15)*4;
        int cl = pass*16 + (t >> 4);
        tile[(hl+0)*66 + cl] = v.x;
        tile[(hl+1)*66 + cl] = v.y;
        tile[(hl+2)*66 + cl] = v.z;
        tile[(hl+3)*66 + cl] = v.w;
        float sv = (v.x + v.y) + (v.z + v.w);
        #pragma unroll
        for (int o = 1; o < 16; o <<= 1) sv += __shfl_xor(sv, o);
        if ((lane & 15) == 0) csum[cl] = sv;
    }
    __syncthreads();
    {
        int hl = t >> 2, cs = (t & 3)*16;
        short8 o0, o1;
        #pragma unroll
        for (int j = 0; j < 8; ++j) o0[j] = (short)f2h(tile[hl*66 + cs + j]);
        #pragma unroll
        for (int j = 0; j < 8; ++j) o1[j] = (short)f2h(tile[hl*66 + cs + 8 + j]);
        size_t m = (size_t)n*HWSZ + hwb + hl;
        ushort* dst = xT + m*CCH + cb + cs;
        *(short8*)dst       = o0;
        *(short8*)(dst + 8) = o1;
    }
    if (t < 64) atomicAdd(&stats[S_MN + cb + t], csum[t]);
}

// ---------------- K_stats1: mn, offs ----------------
__global__ void k_stats1(const float* __restrict__ u, float* __restrict__ stats){
    int i = threadIdx.x;
    __shared__ float mn[256];
    float m = stats[S_MN + i] * (1.f/(float)MCOLS);
    stats[S_MN + i] = m;
    mn[i] = m;
    __syncthreads();
    float o = 0.f;
    for (int c = 0; c < CCH; ++c) o += u[(size_t)c*CCH + i] * mn[c];
    stats[S_OFFS + i] = o;
}

// ---------------- K_gemm1: pT[m][i]=fp16(clamp(uT*xb-offs)); minmax partials ----------------
__global__ __launch_bounds__(256) void k_gemm1(const ushort* __restrict__ xT,
                                               const ushort* __restrict__ uTh,
                                               const float* __restrict__ clampVal,
                                               const float* __restrict__ stats,
                                               ushort* __restrict__ pT,
                                               float* __restrict__ pmin,
                                               float* __restrict__ pmax){
    __shared__ ushort sU[128*256];   // 64 KB, XOR-swizzled 16B chunks
    const int m0 = blockIdx.x*128, i0 = blockIdx.y*128;
    const int t = threadIdx.x, lane = t & 63, wm = t >> 6;
    const int col = lane & 15, quad = lane >> 4;
    #pragma unroll
    for (int j = 0; j < 16; ++j){
        int cid = j*256 + t;
        int row = cid >> 5, c = cid & 31;
        gld_lds16(uTh + (size_t)(i0+row)*CCH + ((c ^ (row & 7))*8), sU + cid*8);
    }
    floatx4 acc[8][2] = {};
    __syncthreads();
    const ushort* xbase = xT + (size_t)(m0 + wm*32 + col)*CCH + quad*8;
    #pragma unroll
    for (int ks = 0; ks < 8; ++ks){
        half8 b0 = __builtin_bit_cast(half8, *(const short8*)(xbase + ks*32));
        half8 b1 = __builtin_bit_cast(half8, *(const short8*)(xbase + 16*CCH + ks*32));
        #pragma unroll
        for (int fi = 0; fi < 8; ++fi){
            int chunk = (ks*4 + quad) ^ (col & 7);
            half8 a = __builtin_bit_cast(half8, *(const short8*)(sU + (fi*16 + col)*CCH + chunk*8));
            acc[fi][0] = __builtin_amdgcn_mfma_f32_16x16x32_f16(a, b0, acc[fi][0], 0, 0, 0);
            acc[fi][1] = __builtin_amdgcn_mfma_f32_16x16x32_f16(a, b1, acc[fi][1], 0, 0, 0);
        }
    }
    const int R = (blockIdx.y*MB + blockIdx.x)*4 + wm;
    #pragma unroll
    for (int fi = 0; fi < 8; ++fi){
        float off[4], cv[4], mnv[4], mxv[4];
        #pragma unroll
        for (int r = 0; r < 4; ++r){
            int ig = i0 + fi*16 + quad*4 + r;
            off[r] = stats[S_OFFS + ig];
            cv[r]  = clampVal[ig];
            mnv[r] =  __builtin_inff();
            mxv[r] = -__builtin_inff();
        }
        #pragma unroll
        for (int fm = 0; fm < 2; ++fm){
            int m = m0 + wm*32 + fm*16 + col;
            ushort pk[4];
            #pragma unroll
            for (int r = 0; r < 4; ++r){
                float v = acc[fi][fm][r] - off[r];
                v = fminf(fmaxf(v, -cv[r]), cv[r]);
                ushort h = f2h(v);
                float vr = h2f(h);
                pk[r] = h;
                mnv[r] = fminf(mnv[r], vr);
                mxv[r] = fmaxf(mxv[r], vr);
            }
            ushort4 q4 = make_ushort4(pk[0], pk[1], pk[2], pk[3]);
            *(ushort4*)(pT + (size_t)m*CCH + i0 + fi*16 + quad*4) = q4;
        }
        #pragma unroll
        for (int r = 0; r < 4; ++r){
            float mn = mnv[r], mx = mxv[r];
            #pragma unroll
            for (int o = 1; o < 16; o <<= 1){
                mn = fminf(mn, __shfl_xor(mn, o));
                mx = fmaxf(mx, __shfl_xor(mx, o));
            }
            if (col == 0){
                int il = fi*16 + quad*4 + r;
                pmin[(size_t)R*128 + il] = mn;
                pmax[(size_t)R*128 + il] = mx;
            }
        }
    }
}

// ---------------- K_mmred: reduce minmax partials -> stats (few atomics) ----------------
__global__ __launch_bounds__(128) void k_mmred(const float* __restrict__ pmin,
                                               const float* __restrict__ pmax,
                                               float* __restrict__ stats){
    const int ib = blockIdx.x, sl = blockIdx.y, il = threadIdx.x;
    float mn = __builtin_inff(), mx = -__builtin_inff();
    const int base = ib*3136 + sl*196;
    for (int r = 0; r < 196; ++r){
        mn = fminf(mn, pmin[(size_t)(base + r)*128 + il]);
        mx = fmaxf(mx, pmax[(size_t)(base + r)*128 + il]);
    }
    atomicMinF(&stats[S_DMIN + ib*128 + il], mn);
    atomicMaxF(&stats[S_DMAX + ib*128 + il], mx);
}

// ---------------- K_qsum: read-only quantized row sums -> partials ----------------
__global__ __launch_bounds__(256) void k_qsum(const ushort* __restrict__ pT,
                                              const int* __restrict__ abw,
                                              const float* __restrict__ stats,
                                              float* __restrict__ qsump){
    const int t = threadIdx.x, b = blockIdx.x;
    const int ic = (t & 31)*8, ml = t >> 5;
    const int ab = *abw;
    const float lv = (float)(((ab < 17) ? (1 << ab) : 2) - 1);
    float dmn[8], scl[8], stp[8];
    #pragma unroll
    for (int j = 0; j < 8; ++j){
        float dmax = stats[S_DMAX + ic + j], dmin = stats[S_DMIN + ic + j];
        float rng = dmax - dmin;
        bool doq = (ab < 17) && (rng > 0.f);
        scl[j] = doq ? lv / rng : 0.f;
        stp[j] = doq ? rng / lv : 0.f;
        dmn[j] = dmin;
    }
    float s[8] = {0,0,0,0,0,0,0,0};
    for (int r = 0; r < 49; ++r){
        int m = b*392 + r*8 + ml;
        short8 pv = *(const short8*)(pT + (size_t)m*CCH + ic);
        #pragma unroll
        for (int j = 0; j < 8; ++j){
            float f = h2f((ushort)pv[j]);
            if (scl[j] > 0.f){
                f = fmaf(rintf((f - dmn[j])*scl[j]), stp[j], dmn[j]);
                f = h2f(f2h(f));              // match gemm2's fp16 B-operand exactly
            }
            s[j] += f;
        }
    }
    __shared__ float red[256*8];
    #pragma unroll
    for (int j = 0; j < 8; ++j) red[(ic + j)*8 + ml] = s[j];
    __syncthreads();
    float tot = 0.f;
    #pragma unroll
    for (int q = 0; q < 8; ++q) tot += red[t*8 + q];
    qsump[b*256 + t] = tot;
}

// ---------------- K_stats2: qmean, scale/step, rowadd ----------------
__global__ void k_stats2(const float* __restrict__ u, const int* __restrict__ abw,
                         const float* __restrict__ qsump, float* __restrict__ stats){
    int i = threadIdx.x;
    __shared__ float qm[256];
    float s = 0.f;
    for (int b = 0; b < 256; ++b) s += qsump[b*256 + i];
    float qmean = s * (1.f/(float)MCOLS);
    qm[i] = qmean;
    stats[S_QSUM + i] = qmean;
    int ab = *abw;
    float dmax = stats[S_DMAX + i], dmin = stats[S_DMIN + i], rng = dmax - dmin;
    bool doq = (ab < 17) && (rng > 0.f);
    float lv = (float)(((ab < 17) ? (1 << ab) : 2) - 1);
    stats[S_SCALE + i] = doq ? lv / rng : 0.f;
    stats[S_STEP + i]  = doq ? rng / lv : 0.f;
    __syncthreads();
    float rs = 0.f;
    for (int c = 0; c < CCH; ++c) rs += u[(size_t)i*CCH + c] * qm[c];
    stats[S_ROWADD + i] = stats[S_MN + i] - rs;
}

// ---------------- K_gemm2: out = u*q(pT) + rowadd (NCHW fp32) ----------------
__global__ __launch_bounds__(256) void k_gemm2(const ushort* __restrict__ pT,
                                               const ushort* __restrict__ uh,
                                               float* __restrict__ out,
                                               const float* __restrict__ stats){
    __shared__ ushort sU[128*256];
    const int m0 = blockIdx.x*128, i0 = blockIdx.y*128;
    const int t = threadIdx.x, lane = t & 63, wm = t >> 6;
    const int col = lane & 15, quad = lane >> 4;
    #pragma unroll
    for (int j = 0; j < 16; ++j){
        int cid = j*256 + t;
        int row = cid >> 5, c = cid & 31;
        gld_lds16(uh + (size_t)(i0+row)*CCH + ((c ^ (row & 7))*8), sU + cid*8);
    }
    floatx4 acc[8][2] = {};
    __syncthreads();
    const ushort* pbase = pT + (size_t)(m0 + wm*32 + col)*CCH + quad*8;
    #pragma unroll
    for (int ks = 0; ks < 8; ++ks){
        const int w0 = ks*32 + quad*8;
        float dmn[8], scl[8], stp[8];
        *(float4*)&dmn[0] = *(const float4*)&stats[S_DMIN  + w0];
        *(float4*)&dmn[4] = *(const float4*)&stats[S_DMIN  + w0 + 4];
        *(float4*)&scl[0] = *(const float4*)&stats[S_SCALE + w0];
        *(float4*)&scl[4] = *(const float4*)&stats[S_SCALE + w0 + 4];
        *(float4*)&stp[0] = *(const float4*)&stats[S_STEP  + w0];
        *(float4*)&stp[4] = *(const float4*)&stats[S_STEP  + w0 + 4];
        half8 b[2];
        #pragma unroll
        for (int fm = 0; fm < 2; ++fm){
            short8 pv = *(const short8*)(pbase + fm*16*CCH + ks*32);
            #pragma unroll
            for (int j = 0; j < 8; ++j){
                float f = h2f((ushort)pv[j]);
                if (scl[j] > 0.f)
                    f = fmaf(rintf((f - dmn[j])*scl[j]), stp[j], dmn[j]);
                b[fm][j] = (_Float16)f;
            }
        }
        #pragma unroll
        for (int fi = 0; fi < 8; ++fi){
            int chunk = (ks*4 + quad) ^ (col & 7);
            half8 a = __builtin_bit_cast(half8, *(const short8*)(sU + (fi*16 + col)*CCH + chunk*8));
            acc[fi][0] = __builtin_amdgcn_mfma_f32_16x16x32_f16(a, b[0], acc[fi][0], 0, 0, 0);
            acc[fi][1] = __builtin_amdgcn_mfma_f32_16x16x32_f16(a, b[1], acc[fi][1], 0, 0, 0);
        }
    }
    #pragma unroll
    for (int fm = 0; fm < 2; ++fm){
        int m = m0 + wm*32 + fm*16 + col;
        int n = m / HWSZ;
        int hw = m - n*HWSZ;
        size_t obase = ((size_t)(n*CCH))*HWSZ + hw;
        #pragma unroll
        for (int fi = 0; fi < 8; ++fi)
            #pragma unroll
            for (int r = 0; r < 4; ++r){
                int ig = i0 + fi*16 + quad*4 + r;
                out[obase + (size_t)ig*HWSZ] = acc[fi][fm][r] + stats[S_ROWADD + ig];
            }
    }
}

extern "C" void kernel_launch(void* const* d_in, const int* in_sizes, int n_in,
                              void* d_out, int out_size, void* d_ws, size_t ws_size,
                              hipStream_t stream){
    const float* x  = (const float*)d_in[0];
    const float* u  = (const float*)d_in[1];
    const float* cv = (const float*)d_in[2];
    const int*   ab = (const int*)d_in[3];
    float* out = (float*)d_out;

    // d_ws: pT + u halves + stats
    ushort* pT   = (ushort*)d_ws;                      // 51.4 MB
    ushort* uTh  = pT + (size_t)MCOLS*CCH;
    ushort* uh   = uTh + CCH*CCH;
    float*  stats = (float*)(uh + CCH*CCH);

    // d_out doubles as scratch until k_gemm2 (all dead by then)
    ushort* xT   = (ushort*)d_out;                     // 51.4 MB
    float*  pmin = (float*)((char*)d_out + (size_t)MCOLS*CCH*2);
    float*  pmax = pmin + (size_t)MB*2*4*128;          // 6272*128
    float*  qsump = pmax + (size_t)MB*2*4*128;         // 256*256

    k_init  <<<8, 256, 0, stream>>>(stats);
    k_prep  <<<256, 256, 0, stream>>>(u, uTh, uh);
    k_trans <<<dim3(49, 4, 32), 256, 0, stream>>>(x, xT, stats);
    k_stats1<<<1, 256, 0, stream>>>(u, stats);
    k_gemm1 <<<dim3(MB, 2), 256, 0, stream>>>(xT, uTh, cv, stats, pT, pmin, pmax);
    k_mmred <<<dim3(2, 16), 128, 0, stream>>>(pmin, pmax, stats);
    k_qsum  <<<256, 256, 0, stream>>>(pT, ab, stats, qsump);
    k_stats2<<<1, 256, 0, stream>>>(u, ab, qsump, stats);
    k_gemm2 <<<dim3(MB, 2), 256, 0, stream>>>(pT, uh, out, stats);
}